// Round 3
// baseline (559.647 us; speedup 1.0000x reference)
//
#include <hip/hip_runtime.h>
#include <math.h>

// Problem constants
#define SEQ    2048
#define DMODEL 1024
#define NHEAD  16
#define HDIM   64
#define MAXP   512
#define NBATCH 2
#define MTOT   (NBATCH * SEQ)   // 4096 rows
#define PAD    72               // LDS row stride (elems) for attn tiles

typedef short s16x8 __attribute__((ext_vector_type(8)));   // 8 bf16 bit-patterns
typedef float f32x4 __attribute__((ext_vector_type(4)));

__device__ __forceinline__ unsigned short f2bf(float f) {
    unsigned u = __float_as_uint(f);
    return (unsigned short)((u + 0x7FFFu + ((u >> 16) & 1u)) >> 16);  // RNE
}
__device__ __forceinline__ float bf2f(unsigned short h) {
    return __uint_as_float(((unsigned)h) << 16);
}

// ---------------------------------------------------------------------------
// split_rows: fp32[n] -> hi/lo bf16 arrays, same layout. n4 = n/4.
// ---------------------------------------------------------------------------
__global__ __launch_bounds__(256) void split_rows(
    const float* __restrict__ in, unsigned short* __restrict__ hi,
    unsigned short* __restrict__ lo, int n4)
{
    int i = blockIdx.x * 256 + threadIdx.x;
    if (i >= n4) return;
    float4 v = ((const float4*)in)[i];
    ushort4 h, l;
    h.x = f2bf(v.x); l.x = f2bf(v.x - bf2f(h.x));
    h.y = f2bf(v.y); l.y = f2bf(v.y - bf2f(h.y));
    h.z = f2bf(v.z); l.z = f2bf(v.z - bf2f(h.z));
    h.w = f2bf(v.w); l.w = f2bf(v.w - bf2f(h.w));
    ((ushort4*)hi)[i] = h;
    ((ushort4*)lo)[i] = l;
}

// ---------------------------------------------------------------------------
// split_transpose: W[1024][1024] fp32 -> Wt hi/lo bf16, Wt[col][k] = W[k][col]
// ---------------------------------------------------------------------------
__global__ __launch_bounds__(256) void split_transpose(
    const float* __restrict__ W, unsigned short* __restrict__ th,
    unsigned short* __restrict__ tl)
{
    __shared__ float tile[32][33];
    const int bx = blockIdx.x * 32;   // col block
    const int by = blockIdx.y * 32;   // k block
    const int tx = threadIdx.x & 31, ty0 = threadIdx.x >> 5;
    #pragma unroll
    for (int i = 0; i < 4; ++i) {
        int ty = ty0 + i * 8;
        tile[ty][tx] = W[(size_t)(by + ty) * DMODEL + bx + tx];
    }
    __syncthreads();
    #pragma unroll
    for (int i = 0; i < 4; ++i) {
        int ty = ty0 + i * 8;
        float v = tile[tx][ty];  // = W[by+tx][bx+ty]
        unsigned short h = f2bf(v);
        unsigned short l = f2bf(v - bf2f(h));
        size_t o = (size_t)(bx + ty) * DMODEL + by + tx;
        th[o] = h;
        tl[o] = l;
    }
}

// ---------------------------------------------------------------------------
// Split-bf16 3-pass MFMA GEMM: Y[4096][1024] = A * B, A hi/lo row-major [m][k],
// B TRANSPOSED hi/lo [col][k]. 128x128 tile, BK=32, 4 waves (2x2), 4x4 frags
// of mfma_f32_16x16x32_bf16 each. acc += Ah*Bh + Ah*Bl + Al*Bh (fp32 accum).
// mode 0: write head-split SPLIT bf16 (Yh/Yl) in [B,H,S,HD] layout.
// mode 1: write fp32 Y[m][n] = acc + bias[n].
// ---------------------------------------------------------------------------
__global__ __launch_bounds__(256, 2) void gemm_mfma(
    const unsigned short* __restrict__ Ah_g, const unsigned short* __restrict__ Al_g,
    const unsigned short* __restrict__ Bh_g, const unsigned short* __restrict__ Bl_g,
    const float* __restrict__ bias, float* __restrict__ Yf,
    unsigned short* __restrict__ Yh, unsigned short* __restrict__ Yl, int mode)
{
    __shared__ __align__(16) unsigned short Ah[128 * 32], Al[128 * 32];
    __shared__ __align__(16) unsigned short Bh[128 * 32], Bl[128 * 32];

    const int tid = threadIdx.x;
    const int lane = tid & 63, wid = tid >> 6;
    const int wr = wid >> 1, wc = wid & 1;
    const int m0 = blockIdx.y * 128, n0 = blockIdx.x * 128;

    const int srow = tid >> 2;
    const int skb = (tid & 3) * 8;
    const size_t aoff0 = (size_t)(m0 + srow) * DMODEL + skb;
    const size_t aoff1 = (size_t)(m0 + srow + 64) * DMODEL + skb;
    const size_t boff0 = (size_t)(n0 + srow) * DMODEL + skb;
    const size_t boff1 = (size_t)(n0 + srow + 64) * DMODEL + skb;
    const int lw = srow * 32 + skb;

    uint4 rah0 = *(const uint4*)(Ah_g + aoff0), rah1 = *(const uint4*)(Ah_g + aoff1);
    uint4 ral0 = *(const uint4*)(Al_g + aoff0), ral1 = *(const uint4*)(Al_g + aoff1);
    uint4 rbh0 = *(const uint4*)(Bh_g + boff0), rbh1 = *(const uint4*)(Bh_g + boff1);
    uint4 rbl0 = *(const uint4*)(Bl_g + boff0), rbl1 = *(const uint4*)(Bl_g + boff1);

    f32x4 acc[4][4] = {};

    const int fr = lane & 15;
    const int fk = (lane >> 4) * 8;

    for (int t = 0; t < DMODEL / 32; ++t) {
        __syncthreads();
        *(uint4*)&Ah[lw] = rah0; *(uint4*)&Ah[lw + 64 * 32] = rah1;
        *(uint4*)&Al[lw] = ral0; *(uint4*)&Al[lw + 64 * 32] = ral1;
        *(uint4*)&Bh[lw] = rbh0; *(uint4*)&Bh[lw + 64 * 32] = rbh1;
        *(uint4*)&Bl[lw] = rbl0; *(uint4*)&Bl[lw + 64 * 32] = rbl1;
        __syncthreads();
        if (t + 1 < DMODEL / 32) {
            const size_t ko = (size_t)(t + 1) * 32;
            rah0 = *(const uint4*)(Ah_g + aoff0 + ko);
            rah1 = *(const uint4*)(Ah_g + aoff1 + ko);
            ral0 = *(const uint4*)(Al_g + aoff0 + ko);
            ral1 = *(const uint4*)(Al_g + aoff1 + ko);
            rbh0 = *(const uint4*)(Bh_g + boff0 + ko);
            rbh1 = *(const uint4*)(Bh_g + boff1 + ko);
            rbl0 = *(const uint4*)(Bl_g + boff0 + ko);
            rbl1 = *(const uint4*)(Bl_g + boff1 + ko);
        }

        s16x8 fah[4], fal[4], fbh[4], fbl[4];
        #pragma unroll
        for (int mf = 0; mf < 4; ++mf) {
            int r = (wr * 64 + mf * 16 + fr) * 32 + fk;
            fah[mf] = *(const s16x8*)&Ah[r];
            fal[mf] = *(const s16x8*)&Al[r];
        }
        #pragma unroll
        for (int nf = 0; nf < 4; ++nf) {
            int r = (wc * 64 + nf * 16 + fr) * 32 + fk;
            fbh[nf] = *(const s16x8*)&Bh[r];
            fbl[nf] = *(const s16x8*)&Bl[r];
        }
        #pragma unroll
        for (int mf = 0; mf < 4; ++mf)
            #pragma unroll
            for (int nf = 0; nf < 4; ++nf) {
                acc[mf][nf] = __builtin_amdgcn_mfma_f32_16x16x32_bf16(fah[mf], fbh[nf], acc[mf][nf], 0, 0, 0);
                acc[mf][nf] = __builtin_amdgcn_mfma_f32_16x16x32_bf16(fah[mf], fbl[nf], acc[mf][nf], 0, 0, 0);
                acc[mf][nf] = __builtin_amdgcn_mfma_f32_16x16x32_bf16(fal[mf], fbh[nf], acc[mf][nf], 0, 0, 0);
            }
    }

    // epilogue: C/D layout col = lane&15, row = (lane>>4)*4 + r
    #pragma unroll
    for (int mf = 0; mf < 4; ++mf) {
        #pragma unroll
        for (int nf = 0; nf < 4; ++nf) {
            const int col = n0 + wc * 64 + nf * 16 + fr;
            #pragma unroll
            for (int r = 0; r < 4; ++r) {
                const int row = m0 + wr * 64 + mf * 16 + (lane >> 4) * 4 + r;
                const float v = acc[mf][nf][r];
                if (mode == 0) {
                    const int hh = col >> 6, d = col & 63;
                    const int bb = row >> 11, ss = row & (SEQ - 1);
                    size_t idx = ((((size_t)bb * NHEAD + hh) * SEQ + ss) << 6) + d;
                    unsigned short hb = f2bf(v);
                    Yh[idx] = hb;
                    Yl[idx] = f2bf(v - bf2f(hb));
                } else {
                    Yf[(size_t)row * DMODEL + col] = v + bias[col];
                }
            }
        }
    }
}

// ---------------------------------------------------------------------------
// MFMA flash attention, split-bf16 3-pass. Grid (S/64, B*H), 256 thr = 4 waves,
// wave w owns Q rows [i0+16w, i0+16w+16). K/V/Q arrive pre-split hi/lo bf16 in
// [B,H,S,HD]. P is repacked through LDS aliased onto the K buffer. V stored
// transposed [d][j] with j-group XOR swizzle for bank-balanced scatter.
// ---------------------------------------------------------------------------
__global__ __launch_bounds__(256) void attn_mfma(
    const unsigned short* __restrict__ Qh_g, const unsigned short* __restrict__ Ql_g,
    const unsigned short* __restrict__ Kh_g, const unsigned short* __restrict__ Kl_g,
    const unsigned short* __restrict__ Vh_g, const unsigned short* __restrict__ Vl_g,
    const float* __restrict__ pos_emb, float* __restrict__ O)
{
    __shared__ __align__(16) unsigned short kph[64 * PAD];  // K hi, later P hi
    __shared__ __align__(16) unsigned short kpl[64 * PAD];  // K lo, later P lo
    __shared__ __align__(16) unsigned short vth[64 * PAD];  // V^T hi [d][j^swz]
    __shared__ __align__(16) unsigned short vtl[64 * PAD];  // V^T lo
    __shared__ float pe[2 * MAXP + 1];

    const int tid = threadIdx.x;
    const int lane = tid & 63, w = tid >> 6;
    const int ti = blockIdx.x, bh = blockIdx.y;
    const int b = bh >> 4, h = bh & 15;
    const int i0 = ti * 64;

    const size_t hb_off = ((size_t)b * NHEAD + h) * SEQ * HDIM;
    const unsigned short* Qh = Qh_g + hb_off;
    const unsigned short* Ql = Ql_g + hb_off;
    const unsigned short* Kh = Kh_g + hb_off;
    const unsigned short* Kl = Kl_g + hb_off;
    const unsigned short* Vh = Vh_g + hb_off;
    const unsigned short* Vl = Vl_g + hb_off;

    for (int e = tid; e < 2 * MAXP + 1; e += 256)
        pe[e] = pos_emb[(size_t)e * NHEAD + h];

    // ---- Q fragments (A-frag: row = lane&15, k = (lane>>4)*8 + ks*32)
    const int fr = lane & 15;            // frag row / col
    const int fko = (lane >> 4) * 8;     // frag k offset
    const int g = lane >> 4;             // C-layout row group
    s16x8 qfh[2], qfl[2];
    {
        const size_t qrow = (size_t)(i0 + w * 16 + fr) * HDIM;
        #pragma unroll
        for (int ks = 0; ks < 2; ++ks) {
            qfh[ks] = *(const s16x8*)(Qh + qrow + ks * 32 + fko);
            qfl[ks] = *(const s16x8*)(Ql + qrow + ks * 32 + fko);
        }
    }

    f32x4 oacc[4] = {};
    float mrow[4] = {-INFINITY, -INFINITY, -INFINITY, -INFINITY};
    float lrow[4] = {};

    // staging thread mapping: rows (tid>>3)+{0,32}, 16B col chunk (tid&7)*8
    const int strow = tid >> 3;
    const int std0 = (tid & 7) * 8;
    const int svswz = (std0 >> 3) & 7;   // V j-swizzle group = tid&7

    for (int tj = 0; tj <= ti; ++tj) {
        const int j0 = tj * 64;
        __syncthreads();   // (1) prior-iter PV reads of kp*/vt* complete
        #pragma unroll
        for (int rr = 0; rr < 2; ++rr) {
            const int row = strow + rr * 32;
            const size_t gsrc = (size_t)(j0 + row) * HDIM + std0;
            uint4 khv = *(const uint4*)(Kh + gsrc);
            uint4 klv = *(const uint4*)(Kl + gsrc);
            *(uint4*)&kph[row * PAD + std0] = khv;
            *(uint4*)&kpl[row * PAD + std0] = klv;
            uint4 vhv = *(const uint4*)(Vh + gsrc);
            uint4 vlv = *(const uint4*)(Vl + gsrc);
            const unsigned short* hs = (const unsigned short*)&vhv;
            const unsigned short* ls = (const unsigned short*)&vlv;
            const int jsw = row ^ (svswz * 8);
            #pragma unroll
            for (int e = 0; e < 8; ++e) {
                vth[(std0 + e) * PAD + jsw] = hs[e];
                vtl[(std0 + e) * PAD + jsw] = ls[e];
            }
        }
        __syncthreads();   // (2) staging visible

        // ---- QK^T: scores s[nf], C-layout (col j = nf*16+fr, row = g*4+r)
        f32x4 s[4] = {};
        #pragma unroll
        for (int ks = 0; ks < 2; ++ks) {
            #pragma unroll
            for (int nf = 0; nf < 4; ++nf) {
                const int ka = (nf * 16 + fr) * PAD + ks * 32 + fko;
                s16x8 kbh = *(const s16x8*)&kph[ka];
                s16x8 kbl = *(const s16x8*)&kpl[ka];
                s[nf] = __builtin_amdgcn_mfma_f32_16x16x32_bf16(qfh[ks], kbh, s[nf], 0, 0, 0);
                s[nf] = __builtin_amdgcn_mfma_f32_16x16x32_bf16(qfh[ks], kbl, s[nf], 0, 0, 0);
                s[nf] = __builtin_amdgcn_mfma_f32_16x16x32_bf16(qfl[ks], kbh, s[nf], 0, 0, 0);
            }
        }
        __syncthreads();   // (3) all waves done reading K; kp* reusable as P

        // ---- bias + causal mask + online softmax (rows owned: g*4+r)
        float mloc[4] = {-INFINITY, -INFINITY, -INFINITY, -INFINITY};
        #pragma unroll
        for (int nf = 0; nf < 4; ++nf) {
            const int jg = j0 + nf * 16 + fr;
            #pragma unroll
            for (int r = 0; r < 4; ++r) {
                const int ig = i0 + w * 16 + g * 4 + r;
                int rel = jg - ig;
                rel = rel < -MAXP ? -MAXP : (rel > MAXP ? MAXP : rel);
                float sv = s[nf][r] * 0.125f + 1e-9f + pe[rel + MAXP];
                sv = (jg > ig) ? -INFINITY : sv;
                s[nf][r] = sv;
                mloc[r] = fmaxf(mloc[r], sv);
            }
        }
        float lsum[4];
        #pragma unroll
        for (int r = 0; r < 4; ++r) {
            float mx = mloc[r];
            #pragma unroll
            for (int msk = 1; msk < 16; msk <<= 1)
                mx = fmaxf(mx, __shfl_xor(mx, msk, 64));
            const float mnew = fmaxf(mrow[r], mx);
            const float fac = __expf(mrow[r] - mnew);
            mrow[r] = mnew;
            lrow[r] *= fac;
            #pragma unroll
            for (int nf = 0; nf < 4; ++nf) oacc[nf][r] *= fac;
            lsum[r] = 0.f;
        }
        #pragma unroll
        for (int nf = 0; nf < 4; ++nf) {
            #pragma unroll
            for (int r = 0; r < 4; ++r) {
                const float p = __expf(s[nf][r] - mrow[r]);
                lsum[r] += p;
                const unsigned short hb = f2bf(p);
                const int idx = (w * 16 + g * 4 + r) * PAD + nf * 16 + fr;
                kph[idx] = hb;
                kpl[idx] = f2bf(p - bf2f(hb));
            }
        }
        #pragma unroll
        for (int r = 0; r < 4; ++r) {
            float ls = lsum[r];
            #pragma unroll
            for (int msk = 1; msk < 16; msk <<= 1)
                ls += __shfl_xor(ls, msk, 64);
            lrow[r] += ls;
        }
        // P rows are wave-local (written and read by same wave) -> no barrier

        // ---- PV: oacc[nf] += P(16xj) * V^T(d=nf*16+fr, k=j)
        #pragma unroll
        for (int ks = 0; ks < 2; ++ks) {
            const int pa = (w * 16 + fr) * PAD + ks * 32 + fko;
            s16x8 pah = *(const s16x8*)&kph[pa];
            s16x8 pal = *(const s16x8*)&kpl[pa];
            #pragma unroll
            for (int nf = 0; nf < 4; ++nf) {
                const int dr = nf * 16 + fr;
                const int va = dr * PAD + ((ks * 32 + fko) ^ (((dr >> 3) & 7) * 8));
                s16x8 vbh = *(const s16x8*)&vth[va];
                s16x8 vbl = *(const s16x8*)&vtl[va];
                oacc[nf] = __builtin_amdgcn_mfma_f32_16x16x32_bf16(pah, vbh, oacc[nf], 0, 0, 0);
                oacc[nf] = __builtin_amdgcn_mfma_f32_16x16x32_bf16(pah, vbl, oacc[nf], 0, 0, 0);
                oacc[nf] = __builtin_amdgcn_mfma_f32_16x16x32_bf16(pal, vbh, oacc[nf], 0, 0, 0);
            }
        }
    }

    // ---- normalize + write O [M, DMODEL] (merge heads)
    float inv[4];
    #pragma unroll
    for (int r = 0; r < 4; ++r) inv[r] = 1.0f / lrow[r];
    #pragma unroll
    for (int nf = 0; nf < 4; ++nf) {
        #pragma unroll
        for (int r = 0; r < 4; ++r) {
            const size_t m = (size_t)b * SEQ + i0 + w * 16 + g * 4 + r;
            O[m * DMODEL + h * HDIM + nf * 16 + fr] = oacc[nf][r] * inv[r];
        }
    }
}

// ---------------------------------------------------------------------------
extern "C" void kernel_launch(void* const* d_in, const int* in_sizes, int n_in,
                              void* d_out, int out_size, void* d_ws, size_t ws_size,
                              hipStream_t stream) {
    const float* x   = (const float*)d_in[0];
    const float* Wq  = (const float*)d_in[1];
    const float* Wk  = (const float*)d_in[2];
    const float* Wv  = (const float*)d_in[3];
    const float* Wo  = (const float*)d_in[4];
    const float* bo  = (const float*)d_in[5];
    const float* pem = (const float*)d_in[6];
    float* out = (float*)d_out;

    char* w = (char*)d_ws;
    const size_t MB = 1 << 20;
    float* o = (float*)(w + 0 * MB);                        // attn out fp32, 16 MB
    unsigned short* oh = (unsigned short*)(w + 16 * MB);    // 8 MB each
    unsigned short* ol = (unsigned short*)(w + 24 * MB);
    unsigned short* qh = (unsigned short*)(w + 32 * MB);
    unsigned short* ql = (unsigned short*)(w + 40 * MB);
    unsigned short* kh = (unsigned short*)(w + 48 * MB);
    unsigned short* kl = (unsigned short*)(w + 56 * MB);
    unsigned short* vh = (unsigned short*)(w + 64 * MB);
    unsigned short* vl = (unsigned short*)(w + 72 * MB);
    unsigned short* Xh = (unsigned short*)(w + 80 * MB);
    unsigned short* Xl = (unsigned short*)(w + 88 * MB);
    unsigned short* Wqh = (unsigned short*)(w + 96 * MB);   // 2 MB each (transposed)
    unsigned short* Wql = (unsigned short*)(w + 98 * MB);
    unsigned short* Wkh = (unsigned short*)(w + 100 * MB);
    unsigned short* Wkl = (unsigned short*)(w + 102 * MB);
    unsigned short* Wvh = (unsigned short*)(w + 104 * MB);
    unsigned short* Wvl = (unsigned short*)(w + 106 * MB);
    unsigned short* Woh = (unsigned short*)(w + 108 * MB);
    unsigned short* Wol = (unsigned short*)(w + 110 * MB);

    const int nX4 = MTOT * DMODEL / 4;
    split_rows<<<dim3(nX4 / 256), 256, 0, stream>>>(x, Xh, Xl, nX4);

    dim3 tg(32, 32);
    split_transpose<<<tg, 256, 0, stream>>>(Wq, Wqh, Wql);
    split_transpose<<<tg, 256, 0, stream>>>(Wk, Wkh, Wkl);
    split_transpose<<<tg, 256, 0, stream>>>(Wv, Wvh, Wvl);
    split_transpose<<<tg, 256, 0, stream>>>(Wo, Woh, Wol);

    dim3 gg(DMODEL / 128, MTOT / 128);   // (8, 32)
    gemm_mfma<<<gg, 256, 0, stream>>>(Xh, Xl, Wqh, Wql, nullptr, nullptr, qh, ql, 0);
    gemm_mfma<<<gg, 256, 0, stream>>>(Xh, Xl, Wkh, Wkl, nullptr, nullptr, kh, kl, 0);
    gemm_mfma<<<gg, 256, 0, stream>>>(Xh, Xl, Wvh, Wvl, nullptr, nullptr, vh, vl, 0);

    attn_mfma<<<dim3(SEQ / 64, NBATCH * NHEAD), 256, 0, stream>>>(
        qh, ql, kh, kl, vh, vl, pem, o);

    split_rows<<<dim3(nX4 / 256), 256, 0, stream>>>(o, oh, ol, nX4);
    gemm_mfma<<<gg, 256, 0, stream>>>(oh, ol, Woh, Wol, bo, out, nullptr, nullptr, 1);
}

// Round 5
// 389.207 us; speedup vs baseline: 1.4379x; 1.4379x over previous
//
#include <hip/hip_runtime.h>
#include <math.h>

// Problem constants
#define SEQ    2048
#define DMODEL 1024
#define NHEAD  16
#define HDIM   64
#define MAXP   512
#define NBATCH 2
#define MTOT   (NBATCH * SEQ)   // 4096 rows
#define PAD    72               // LDS row stride (elems) for attn tiles
#define NT     (SEQ / 64)       // 32 j-tiles

typedef short s16x8 __attribute__((ext_vector_type(8)));   // 8 bf16 bit-patterns
typedef float f32x4 __attribute__((ext_vector_type(4)));

__device__ __forceinline__ unsigned short f2bf(float f) {
    unsigned u = __float_as_uint(f);
    return (unsigned short)((u + 0x7FFFu + ((u >> 16) & 1u)) >> 16);  // RNE
}
__device__ __forceinline__ float bf2f(unsigned short h) {
    return __uint_as_float(((unsigned)h) << 16);
}
// truncation split: hi = trunc-bf16(v), lo = trunc-bf16(v - hi)  (exact residual)
__device__ __forceinline__ void tsplit(float v, unsigned short& hi, unsigned short& lo) {
    unsigned u = __float_as_uint(v);
    hi = (unsigned short)(u >> 16);
    float rem = v - __uint_as_float(u & 0xFFFF0000u);
    lo = (unsigned short)(__float_as_uint(rem) >> 16);
}

// ---------------------------------------------------------------------------
// split_rows: fp32[n] -> hi/lo bf16 arrays, same layout. n4 = n/4.
// ---------------------------------------------------------------------------
__global__ __launch_bounds__(256) void split_rows(
    const float* __restrict__ in, unsigned short* __restrict__ hi,
    unsigned short* __restrict__ lo, int n4)
{
    int i = blockIdx.x * 256 + threadIdx.x;
    if (i >= n4) return;
    float4 v = ((const float4*)in)[i];
    ushort4 h, l;
    h.x = f2bf(v.x); l.x = f2bf(v.x - bf2f(h.x));
    h.y = f2bf(v.y); l.y = f2bf(v.y - bf2f(h.y));
    h.z = f2bf(v.z); l.z = f2bf(v.z - bf2f(h.z));
    h.w = f2bf(v.w); l.w = f2bf(v.w - bf2f(h.w));
    ((ushort4*)hi)[i] = h;
    ((ushort4*)lo)[i] = l;
}

// ---------------------------------------------------------------------------
// split_transpose: W[1024][1024] fp32 -> Wt hi/lo bf16, Wt[col][k] = W[k][col]
// ---------------------------------------------------------------------------
__global__ __launch_bounds__(256) void split_transpose(
    const float* __restrict__ W, unsigned short* __restrict__ th,
    unsigned short* __restrict__ tl)
{
    __shared__ float tile[32][33];
    const int bx = blockIdx.x * 32;   // col block
    const int by = blockIdx.y * 32;   // k block
    const int tx = threadIdx.x & 31, ty0 = threadIdx.x >> 5;
    #pragma unroll
    for (int i = 0; i < 4; ++i) {
        int ty = ty0 + i * 8;
        tile[ty][tx] = W[(size_t)(by + ty) * DMODEL + bx + tx];
    }
    __syncthreads();
    #pragma unroll
    for (int i = 0; i < 4; ++i) {
        int ty = ty0 + i * 8;
        float v = tile[tx][ty];  // = W[by+tx][bx+ty]
        unsigned short h = f2bf(v);
        unsigned short l = f2bf(v - bf2f(h));
        size_t o = (size_t)(bx + ty) * DMODEL + by + tx;
        th[o] = h;
        tl[o] = l;
    }
}

// ---------------------------------------------------------------------------
// Split-bf16 3-pass MFMA GEMM: Y[4096][1024] = A * B, A hi/lo row-major [m][k],
// B TRANSPOSED hi/lo [col][k]. 128x128 tile, BK=32, 4 waves (2x2), 4x4 frags.
// mode 0: head-split bf16 hi/lo, layout [B,H,S,HD]   (Q, K)
// mode 1: fp32 Y[m][n] = acc + bias[n]               (final out)
// mode 2: head-split bf16 hi/lo TRANSPOSED [B,H,HD,S] (V^T), ushort4 stores
// ---------------------------------------------------------------------------
__global__ __launch_bounds__(256, 2) void gemm_mfma(
    const unsigned short* __restrict__ Ah_g, const unsigned short* __restrict__ Al_g,
    const unsigned short* __restrict__ Bh_g, const unsigned short* __restrict__ Bl_g,
    const float* __restrict__ bias, float* __restrict__ Yf,
    unsigned short* __restrict__ Yh, unsigned short* __restrict__ Yl, int mode)
{
    __shared__ __align__(16) unsigned short Ah[128 * 32], Al[128 * 32];
    __shared__ __align__(16) unsigned short Bh[128 * 32], Bl[128 * 32];

    const int tid = threadIdx.x;
    const int lane = tid & 63, wid = tid >> 6;
    const int wr = wid >> 1, wc = wid & 1;
    const int m0 = blockIdx.y * 128, n0 = blockIdx.x * 128;

    const int srow = tid >> 2;
    const int skb = (tid & 3) * 8;
    const size_t aoff0 = (size_t)(m0 + srow) * DMODEL + skb;
    const size_t aoff1 = (size_t)(m0 + srow + 64) * DMODEL + skb;
    const size_t boff0 = (size_t)(n0 + srow) * DMODEL + skb;
    const size_t boff1 = (size_t)(n0 + srow + 64) * DMODEL + skb;
    const int lw = srow * 32 + skb;

    uint4 rah0 = *(const uint4*)(Ah_g + aoff0), rah1 = *(const uint4*)(Ah_g + aoff1);
    uint4 ral0 = *(const uint4*)(Al_g + aoff0), ral1 = *(const uint4*)(Al_g + aoff1);
    uint4 rbh0 = *(const uint4*)(Bh_g + boff0), rbh1 = *(const uint4*)(Bh_g + boff1);
    uint4 rbl0 = *(const uint4*)(Bl_g + boff0), rbl1 = *(const uint4*)(Bl_g + boff1);

    f32x4 acc[4][4] = {};

    const int fr = lane & 15;
    const int fk = (lane >> 4) * 8;

    for (int t = 0; t < DMODEL / 32; ++t) {
        __syncthreads();
        *(uint4*)&Ah[lw] = rah0; *(uint4*)&Ah[lw + 64 * 32] = rah1;
        *(uint4*)&Al[lw] = ral0; *(uint4*)&Al[lw + 64 * 32] = ral1;
        *(uint4*)&Bh[lw] = rbh0; *(uint4*)&Bh[lw + 64 * 32] = rbh1;
        *(uint4*)&Bl[lw] = rbl0; *(uint4*)&Bl[lw + 64 * 32] = rbl1;
        __syncthreads();
        if (t + 1 < DMODEL / 32) {
            const size_t ko = (size_t)(t + 1) * 32;
            rah0 = *(const uint4*)(Ah_g + aoff0 + ko);
            rah1 = *(const uint4*)(Ah_g + aoff1 + ko);
            ral0 = *(const uint4*)(Al_g + aoff0 + ko);
            ral1 = *(const uint4*)(Al_g + aoff1 + ko);
            rbh0 = *(const uint4*)(Bh_g + boff0 + ko);
            rbh1 = *(const uint4*)(Bh_g + boff1 + ko);
            rbl0 = *(const uint4*)(Bl_g + boff0 + ko);
            rbl1 = *(const uint4*)(Bl_g + boff1 + ko);
        }

        s16x8 fah[4], fal[4], fbh[4], fbl[4];
        #pragma unroll
        for (int mf = 0; mf < 4; ++mf) {
            int r = (wr * 64 + mf * 16 + fr) * 32 + fk;
            fah[mf] = *(const s16x8*)&Ah[r];
            fal[mf] = *(const s16x8*)&Al[r];
        }
        #pragma unroll
        for (int nf = 0; nf < 4; ++nf) {
            int r = (wc * 64 + nf * 16 + fr) * 32 + fk;
            fbh[nf] = *(const s16x8*)&Bh[r];
            fbl[nf] = *(const s16x8*)&Bl[r];
        }
        __builtin_amdgcn_s_setprio(1);
        #pragma unroll
        for (int mf = 0; mf < 4; ++mf)
            #pragma unroll
            for (int nf = 0; nf < 4; ++nf) {
                acc[mf][nf] = __builtin_amdgcn_mfma_f32_16x16x32_bf16(fah[mf], fbh[nf], acc[mf][nf], 0, 0, 0);
                acc[mf][nf] = __builtin_amdgcn_mfma_f32_16x16x32_bf16(fah[mf], fbl[nf], acc[mf][nf], 0, 0, 0);
                acc[mf][nf] = __builtin_amdgcn_mfma_f32_16x16x32_bf16(fal[mf], fbh[nf], acc[mf][nf], 0, 0, 0);
            }
        __builtin_amdgcn_s_setprio(0);
    }

    // epilogue: C/D layout col = lane&15, row = (lane>>4)*4 + r
    #pragma unroll
    for (int mf = 0; mf < 4; ++mf) {
        #pragma unroll
        for (int nf = 0; nf < 4; ++nf) {
            const int col = n0 + wc * 64 + nf * 16 + fr;
            if (mode == 2) {
                const int hh = col >> 6, d = col & 63;
                const int row0 = m0 + wr * 64 + mf * 16 + (lane >> 4) * 4;
                const int bb = row0 >> 11, ss = row0 & (SEQ - 1);
                const size_t idx = (((size_t)bb * NHEAD + hh) * HDIM + d) * SEQ + ss;
                ushort4 hv, lv;
                {
                    float v0 = acc[mf][nf][0], v1 = acc[mf][nf][1];
                    float v2 = acc[mf][nf][2], v3 = acc[mf][nf][3];
                    hv.x = f2bf(v0); lv.x = f2bf(v0 - bf2f(hv.x));
                    hv.y = f2bf(v1); lv.y = f2bf(v1 - bf2f(hv.y));
                    hv.z = f2bf(v2); lv.z = f2bf(v2 - bf2f(hv.z));
                    hv.w = f2bf(v3); lv.w = f2bf(v3 - bf2f(hv.w));
                }
                *(ushort4*)(Yh + idx) = hv;
                *(ushort4*)(Yl + idx) = lv;
            } else {
                #pragma unroll
                for (int r = 0; r < 4; ++r) {
                    const int row = m0 + wr * 64 + mf * 16 + (lane >> 4) * 4 + r;
                    const float v = acc[mf][nf][r];
                    if (mode == 0) {
                        const int hh = col >> 6, d = col & 63;
                        const int bb = row >> 11, ss = row & (SEQ - 1);
                        size_t idx = ((((size_t)bb * NHEAD + hh) * SEQ + ss) << 6) + d;
                        unsigned short hb = f2bf(v);
                        Yh[idx] = hb;
                        Yl[idx] = f2bf(v - bf2f(hb));
                    } else {
                        Yf[(size_t)row * DMODEL + col] = v + bias[col];
                    }
                }
            }
        }
    }
}

// ---------------------------------------------------------------------------
// MFMA flash attention, split-bf16 3-pass. Grid (NT/2, B*H), 256 thr = 4 waves.
// Block processes Q-tile pair {pi, NT-1-pi} => uniform 33 j-tiles per block.
// V arrives pre-transposed globally [B,H,HD,S] -> pure 16B staging, no scatter.
// Register prefetch of next K/V tile hides HBM latency under MFMA+softmax.
// P aliases the K LDS buffer after QK^T. Epilogue writes split bf16 Oh/Ol.
// ---------------------------------------------------------------------------
__global__ __launch_bounds__(256, 2) void attn_mfma(
    const unsigned short* __restrict__ Qh_g, const unsigned short* __restrict__ Ql_g,
    const unsigned short* __restrict__ Kh_g, const unsigned short* __restrict__ Kl_g,
    const unsigned short* __restrict__ Vth_g, const unsigned short* __restrict__ Vtl_g,
    const float* __restrict__ pos_emb,
    unsigned short* __restrict__ Oh_g, unsigned short* __restrict__ Ol_g)
{
    __shared__ __align__(16) unsigned short kph[64 * PAD];  // K hi -> P hi
    __shared__ __align__(16) unsigned short kpl[64 * PAD];  // K lo -> P lo
    __shared__ __align__(16) unsigned short vth[64 * PAD];  // V^T hi [d][j]
    __shared__ __align__(16) unsigned short vtl[64 * PAD];  // V^T lo [d][j]
    __shared__ float pe[2 * MAXP + 1];

    const int tid = threadIdx.x;
    const int lane = tid & 63, w = tid >> 6;
    const int pi = blockIdx.x, bh = blockIdx.y;
    const int b = bh >> 4, h = bh & 15;

    const size_t hboff = ((size_t)b * NHEAD + h) * SEQ * HDIM;
    const unsigned short* Qh = Qh_g + hboff;
    const unsigned short* Ql = Ql_g + hboff;
    const unsigned short* Kh = Kh_g + hboff;
    const unsigned short* Kl = Kl_g + hboff;
    const unsigned short* Vth = Vth_g + hboff;   // [HDIM][SEQ]
    const unsigned short* Vtl = Vtl_g + hboff;

    for (int e = tid; e <= 2 * MAXP; e += 256)
        pe[e] = pos_emb[(size_t)e * NHEAD + h];

    const int fr = lane & 15;          // frag row/col within 16
    const int g = lane >> 4;           // C-layout row group; frag k off = g*8
    const int fko = g * 8;

    const int strow = tid >> 3;        // staging row 0..31 (+32)
    const int std0 = (tid & 7) * 8;    // staging 16B chunk (elems)

    uint4 rkh0, rkh1, rkl0, rkl1, rvh0, rvh1, rvl0, rvl1;
#define LDREGS(J0) do {                                                         \
    const unsigned short* kp_ = Kh + (size_t)((J0) + strow) * HDIM + std0;      \
    rkh0 = *(const uint4*)kp_;  rkh1 = *(const uint4*)(kp_ + 32 * HDIM);        \
    const unsigned short* klp_ = Kl + (size_t)((J0) + strow) * HDIM + std0;     \
    rkl0 = *(const uint4*)klp_; rkl1 = *(const uint4*)(klp_ + 32 * HDIM);       \
    const unsigned short* vhp_ = Vth + (size_t)strow * SEQ + (J0) + std0;       \
    rvh0 = *(const uint4*)vhp_; rvh1 = *(const uint4*)(vhp_ + 32 * SEQ);        \
    const unsigned short* vlp_ = Vtl + (size_t)strow * SEQ + (J0) + std0;       \
    rvl0 = *(const uint4*)vlp_; rvl1 = *(const uint4*)(vlp_ + 32 * SEQ);        \
} while (0)

    for (int half = 0; half < 2; ++half) {
        const int qt = half ? (NT - 1 - pi) : pi;
        const int i0 = qt * 64;

        // Q fragments: A-frag row = fr, k = fko + ks*32
        s16x8 qfh[2], qfl[2];
        {
            const size_t qrow = (size_t)(i0 + w * 16 + fr) * HDIM;
            qfh[0] = *(const s16x8*)(Qh + qrow + fko);
            qfh[1] = *(const s16x8*)(Qh + qrow + 32 + fko);
            qfl[0] = *(const s16x8*)(Ql + qrow + fko);
            qfl[1] = *(const s16x8*)(Ql + qrow + 32 + fko);
        }

        f32x4 oacc[4] = {};
        float mrow[4] = {-INFINITY, -INFINITY, -INFINITY, -INFINITY};
        float lrow[4] = {};

        LDREGS(0);

        for (int tj = 0; tj <= qt; ++tj) {
            const int j0 = tj * 64;
            __syncthreads();   // (1) prior-iter LDS readers done
            *(uint4*)&kph[strow * PAD + std0] = rkh0;
            *(uint4*)&kph[(strow + 32) * PAD + std0] = rkh1;
            *(uint4*)&kpl[strow * PAD + std0] = rkl0;
            *(uint4*)&kpl[(strow + 32) * PAD + std0] = rkl1;
            *(uint4*)&vth[strow * PAD + std0] = rvh0;
            *(uint4*)&vth[(strow + 32) * PAD + std0] = rvh1;
            *(uint4*)&vtl[strow * PAD + std0] = rvl0;
            *(uint4*)&vtl[(strow + 32) * PAD + std0] = rvl1;
            __syncthreads();   // (2) staging visible
            if (tj < qt) LDREGS(j0 + 64);   // prefetch next tile into regs

            // ---- QK^T: C-layout (col j = nf*16+fr, row = g*4+r)
            f32x4 s[4] = {};
            __builtin_amdgcn_s_setprio(1);
            #pragma unroll
            for (int ks = 0; ks < 2; ++ks) {
                #pragma unroll
                for (int nf = 0; nf < 4; ++nf) {
                    const int ka = (nf * 16 + fr) * PAD + ks * 32 + fko;
                    s16x8 kbh = *(const s16x8*)&kph[ka];
                    s16x8 kbl = *(const s16x8*)&kpl[ka];
                    s[nf] = __builtin_amdgcn_mfma_f32_16x16x32_bf16(qfh[ks], kbh, s[nf], 0, 0, 0);
                    s[nf] = __builtin_amdgcn_mfma_f32_16x16x32_bf16(qfh[ks], kbl, s[nf], 0, 0, 0);
                    s[nf] = __builtin_amdgcn_mfma_f32_16x16x32_bf16(qfl[ks], kbh, s[nf], 0, 0, 0);
                }
            }
            __builtin_amdgcn_s_setprio(0);
            __syncthreads();   // (3) K reads done; kp* becomes P

            // ---- bias + mask + online softmax
            float mloc[4] = {-INFINITY, -INFINITY, -INFINITY, -INFINITY};
            if (qt - tj >= 9) {
                // all rel <= -512: uniform bias pe[0]
                const float c0 = 1e-9f + pe[0];
                #pragma unroll
                for (int nf = 0; nf < 4; ++nf)
                    #pragma unroll
                    for (int r = 0; r < 4; ++r) {
                        float sv = s[nf][r] * 0.125f + c0;
                        s[nf][r] = sv;
                        mloc[r] = fmaxf(mloc[r], sv);
                    }
            } else if (tj < qt) {
                // no mask; only low clamp possible
                #pragma unroll
                for (int nf = 0; nf < 4; ++nf) {
                    const int jg = j0 + nf * 16 + fr;
                    #pragma unroll
                    for (int r = 0; r < 4; ++r) {
                        const int ig = i0 + w * 16 + g * 4 + r;
                        int rel = jg - ig;
                        rel = rel < -MAXP ? -MAXP : rel;
                        float sv = s[nf][r] * 0.125f + 1e-9f + pe[rel + MAXP];
                        s[nf][r] = sv;
                        mloc[r] = fmaxf(mloc[r], sv);
                    }
                }
            } else {
                // diagonal tile: |rel| <= 63, causal mask
                #pragma unroll
                for (int nf = 0; nf < 4; ++nf) {
                    const int jg = j0 + nf * 16 + fr;
                    #pragma unroll
                    for (int r = 0; r < 4; ++r) {
                        const int ig = i0 + w * 16 + g * 4 + r;
                        float sv = s[nf][r] * 0.125f + 1e-9f + pe[jg - ig + MAXP];
                        sv = (jg > ig) ? -INFINITY : sv;
                        s[nf][r] = sv;
                        mloc[r] = fmaxf(mloc[r], sv);
                    }
                }
            }

            float lsum[4];
            #pragma unroll
            for (int r = 0; r < 4; ++r) {
                float mx = mloc[r];
                #pragma unroll
                for (int msk = 1; msk < 16; msk <<= 1)
                    mx = fmaxf(mx, __shfl_xor(mx, msk, 64));
                const float mnew = fmaxf(mrow[r], mx);
                const float fac = __expf(mrow[r] - mnew);
                mrow[r] = mnew;
                lrow[r] *= fac;
                #pragma unroll
                for (int nf = 0; nf < 4; ++nf) oacc[nf][r] *= fac;
                lsum[r] = 0.f;
            }
            #pragma unroll
            for (int nf = 0; nf < 4; ++nf) {
                #pragma unroll
                for (int r = 0; r < 4; ++r) {
                    const float p = __expf(s[nf][r] - mrow[r]);
                    lsum[r] += p;
                    unsigned short hb, lb;
                    tsplit(p, hb, lb);
                    const int idx = (w * 16 + g * 4 + r) * PAD + nf * 16 + fr;
                    kph[idx] = hb;
                    kpl[idx] = lb;
                }
            }
            #pragma unroll
            for (int r = 0; r < 4; ++r) {
                float ls = lsum[r];
                #pragma unroll
                for (int msk = 1; msk < 16; msk <<= 1)
                    ls += __shfl_xor(ls, msk, 64);
                lrow[r] += ls;
            }
            // P rows are wave-local -> no barrier before PV

            // ---- PV: oacc[nf] += P(rows w*16..) * V^T(d = nf*16+fr)
            __builtin_amdgcn_s_setprio(1);
            #pragma unroll
            for (int ks = 0; ks < 2; ++ks) {
                const int pa = (w * 16 + fr) * PAD + ks * 32 + fko;
                s16x8 pah = *(const s16x8*)&kph[pa];
                s16x8 pal = *(const s16x8*)&kpl[pa];
                #pragma unroll
                for (int nf = 0; nf < 4; ++nf) {
                    const int va = (nf * 16 + fr) * PAD + ks * 32 + fko;
                    s16x8 vbh = *(const s16x8*)&vth[va];
                    s16x8 vbl = *(const s16x8*)&vtl[va];
                    oacc[nf] = __builtin_amdgcn_mfma_f32_16x16x32_bf16(pah, vbh, oacc[nf], 0, 0, 0);
                    oacc[nf] = __builtin_amdgcn_mfma_f32_16x16x32_bf16(pah, vbl, oacc[nf], 0, 0, 0);
                    oacc[nf] = __builtin_amdgcn_mfma_f32_16x16x32_bf16(pal, vbh, oacc[nf], 0, 0, 0);
                }
            }
            __builtin_amdgcn_s_setprio(0);
        }

        // ---- normalize + write split O [M, DMODEL] (merge heads)
        float inv[4];
        #pragma unroll
        for (int r = 0; r < 4; ++r) inv[r] = 1.0f / lrow[r];
        #pragma unroll
        for (int nf = 0; nf < 4; ++nf) {
            #pragma unroll
            for (int r = 0; r < 4; ++r) {
                const size_t m = (size_t)b * SEQ + i0 + w * 16 + g * 4 + r;
                const size_t idx = m * DMODEL + h * HDIM + nf * 16 + fr;
                unsigned short hv, lv;
                tsplit(oacc[nf][r] * inv[r], hv, lv);
                Oh_g[idx] = hv;
                Ol_g[idx] = lv;
            }
        }
    }
#undef LDREGS
}

// ---------------------------------------------------------------------------
extern "C" void kernel_launch(void* const* d_in, const int* in_sizes, int n_in,
                              void* d_out, int out_size, void* d_ws, size_t ws_size,
                              hipStream_t stream) {
    const float* x   = (const float*)d_in[0];
    const float* Wq  = (const float*)d_in[1];
    const float* Wk  = (const float*)d_in[2];
    const float* Wv  = (const float*)d_in[3];
    const float* Wo  = (const float*)d_in[4];
    const float* bo  = (const float*)d_in[5];
    const float* pem = (const float*)d_in[6];
    float* out = (float*)d_out;

    char* w = (char*)d_ws;
    const size_t MB = 1 << 20;
    unsigned short* oh  = (unsigned short*)(w + 0 * MB);    // 8 MB each
    unsigned short* ol  = (unsigned short*)(w + 8 * MB);
    unsigned short* qh  = (unsigned short*)(w + 16 * MB);
    unsigned short* ql  = (unsigned short*)(w + 24 * MB);
    unsigned short* kh  = (unsigned short*)(w + 32 * MB);
    unsigned short* kl  = (unsigned short*)(w + 40 * MB);
    unsigned short* vth = (unsigned short*)(w + 48 * MB);   // V^T [B,H,HD,S]
    unsigned short* vtl = (unsigned short*)(w + 56 * MB);
    unsigned short* Xh  = (unsigned short*)(w + 64 * MB);
    unsigned short* Xl  = (unsigned short*)(w + 72 * MB);
    unsigned short* Wqh = (unsigned short*)(w + 80 * MB);   // 2 MB each (transposed)
    unsigned short* Wql = (unsigned short*)(w + 82 * MB);
    unsigned short* Wkh = (unsigned short*)(w + 84 * MB);
    unsigned short* Wkl = (unsigned short*)(w + 86 * MB);
    unsigned short* Wvh = (unsigned short*)(w + 88 * MB);
    unsigned short* Wvl = (unsigned short*)(w + 90 * MB);
    unsigned short* Woh = (unsigned short*)(w + 92 * MB);
    unsigned short* Wol = (unsigned short*)(w + 94 * MB);

    const int nX4 = MTOT * DMODEL / 4;
    split_rows<<<dim3(nX4 / 256), 256, 0, stream>>>(x, Xh, Xl, nX4);

    dim3 tg(32, 32);
    split_transpose<<<tg, 256, 0, stream>>>(Wq, Wqh, Wql);
    split_transpose<<<tg, 256, 0, stream>>>(Wk, Wkh, Wkl);
    split_transpose<<<tg, 256, 0, stream>>>(Wv, Wvh, Wvl);
    split_transpose<<<tg, 256, 0, stream>>>(Wo, Woh, Wol);

    dim3 gg(DMODEL / 128, MTOT / 128);   // (8, 32)
    gemm_mfma<<<gg, 256, 0, stream>>>(Xh, Xl, Wqh, Wql, nullptr, nullptr, qh, ql, 0);
    gemm_mfma<<<gg, 256, 0, stream>>>(Xh, Xl, Wkh, Wkl, nullptr, nullptr, kh, kl, 0);
    gemm_mfma<<<gg, 256, 0, stream>>>(Xh, Xl, Wvh, Wvl, nullptr, nullptr, vth, vtl, 2);

    attn_mfma<<<dim3(NT / 2, NBATCH * NHEAD), 256, 0, stream>>>(
        qh, ql, kh, kl, vth, vtl, pem, oh, ol);

    gemm_mfma<<<gg, 256, 0, stream>>>(oh, ol, Woh, Wol, bo, out, nullptr, nullptr, 1);
}

// Round 6
// 316.096 us; speedup vs baseline: 1.7705x; 1.2313x over previous
//
#include <hip/hip_runtime.h>
#include <math.h>

// Problem constants
#define SEQ    2048
#define DMODEL 1024
#define NHEAD  16
#define HDIM   64
#define MAXP   512
#define NBATCH 2
#define MTOT   (NBATCH * SEQ)   // 4096 rows
#define PAD    68               // LDS row stride (elems) for attn tiles
#define NT     (SEQ / 64)       // 32 j-tiles

typedef short s16x8 __attribute__((ext_vector_type(8)));   // 8 bf16 bit-patterns
typedef float f32x4 __attribute__((ext_vector_type(4)));

typedef unsigned int u32_as1 __attribute__((address_space(1)));
typedef unsigned int u32_as3 __attribute__((address_space(3)));

// async global->LDS, 16B per lane; LDS dest must be wave-uniform base (lane*16 implicit)
__device__ __forceinline__ void gload16(const void* g, void* l) {
    __builtin_amdgcn_global_load_lds((const u32_as1*)g, (u32_as3*)l, 16, 0, 0);
}

__device__ __forceinline__ unsigned short f2bf(float f) {
    unsigned u = __float_as_uint(f);
    return (unsigned short)((u + 0x7FFFu + ((u >> 16) & 1u)) >> 16);  // RNE
}
__device__ __forceinline__ float bf2f(unsigned short h) {
    return __uint_as_float(((unsigned)h) << 16);
}
// truncation split: hi = trunc-bf16(v), lo = trunc-bf16(v - hi)
__device__ __forceinline__ void tsplit(float v, unsigned short& hi, unsigned short& lo) {
    unsigned u = __float_as_uint(v);
    hi = (unsigned short)(u >> 16);
    float rem = v - __uint_as_float(u & 0xFFFF0000u);
    lo = (unsigned short)(__float_as_uint(rem) >> 16);
}

// ---------------------------------------------------------------------------
// split_rows: fp32[n] -> hi/lo bf16 arrays, same layout. n4 = n/4.
// ---------------------------------------------------------------------------
__global__ __launch_bounds__(256) void split_rows(
    const float* __restrict__ in, unsigned short* __restrict__ hi,
    unsigned short* __restrict__ lo, int n4)
{
    int i = blockIdx.x * 256 + threadIdx.x;
    if (i >= n4) return;
    float4 v = ((const float4*)in)[i];
    ushort4 h, l;
    h.x = f2bf(v.x); l.x = f2bf(v.x - bf2f(h.x));
    h.y = f2bf(v.y); l.y = f2bf(v.y - bf2f(h.y));
    h.z = f2bf(v.z); l.z = f2bf(v.z - bf2f(h.z));
    h.w = f2bf(v.w); l.w = f2bf(v.w - bf2f(h.w));
    ((ushort4*)hi)[i] = h;
    ((ushort4*)lo)[i] = l;
}

// ---------------------------------------------------------------------------
// split_transpose: W[1024][1024] fp32 -> Wt hi/lo bf16, Wt[col][k] = W[k][col]
// ---------------------------------------------------------------------------
__global__ __launch_bounds__(256) void split_transpose(
    const float* __restrict__ W, unsigned short* __restrict__ th,
    unsigned short* __restrict__ tl)
{
    __shared__ float tile[32][33];
    const int bx = blockIdx.x * 32;   // col block
    const int by = blockIdx.y * 32;   // k block
    const int tx = threadIdx.x & 31, ty0 = threadIdx.x >> 5;
    #pragma unroll
    for (int i = 0; i < 4; ++i) {
        int ty = ty0 + i * 8;
        tile[ty][tx] = W[(size_t)(by + ty) * DMODEL + bx + tx];
    }
    __syncthreads();
    #pragma unroll
    for (int i = 0; i < 4; ++i) {
        int ty = ty0 + i * 8;
        float v = tile[tx][ty];  // = W[by+tx][bx+ty]
        unsigned short h = f2bf(v);
        unsigned short l = f2bf(v - bf2f(h));
        size_t o = (size_t)(bx + ty) * DMODEL + by + tx;
        th[o] = h;
        tl[o] = l;
    }
}

// ---------------------------------------------------------------------------
// Split-bf16 3-pass MFMA GEMM with global_load_lds staging (m97 2-barrier).
// 128x128 tile, BK=32, 4 waves (2x2), 4x4 frags of mfma_f32_16x16x32_bf16.
// mode 0: fused QKV — blockIdx.x: 24 n-tiles = 3 matrices x 8; which selects
//         B/out. which 0,1 -> head-split bf16 hi/lo [B,H,S,HD] (Q,K);
//         which 2 -> transposed V^T [B,H,HD,S], ushort4 stores.
// mode 1: single B (B0), fp32 out Yf = acc + bias.
// ---------------------------------------------------------------------------
__global__ __launch_bounds__(256, 3) void gemm_mfma(
    const unsigned short* __restrict__ Ah_g, const unsigned short* __restrict__ Al_g,
    const unsigned short* __restrict__ B0h, const unsigned short* __restrict__ B0l,
    const unsigned short* __restrict__ B1h, const unsigned short* __restrict__ B1l,
    const unsigned short* __restrict__ B2h, const unsigned short* __restrict__ B2l,
    const float* __restrict__ bias, float* __restrict__ Yf,
    unsigned short* __restrict__ Y0h, unsigned short* __restrict__ Y0l,
    unsigned short* __restrict__ Y1h, unsigned short* __restrict__ Y1l,
    unsigned short* __restrict__ Y2h, unsigned short* __restrict__ Y2l,
    int mode)
{
    __shared__ __align__(16) unsigned short Ah[128 * 32], Al[128 * 32];
    __shared__ __align__(16) unsigned short Bh[128 * 32], Bl[128 * 32];

    const int tid = threadIdx.x;
    const int lane = tid & 63, wid = tid >> 6;
    const int wr = wid >> 1, wc = wid & 1;
    const int m0 = blockIdx.y * 128;
    const int which = (mode == 0) ? (blockIdx.x >> 3) : 0;
    const int n0 = ((mode == 0) ? (blockIdx.x & 7) : blockIdx.x) * 128;

    const unsigned short* Bh_g = (which == 0) ? B0h : (which == 1 ? B1h : B2h);
    const unsigned short* Bl_g = (which == 0) ? B0l : (which == 1 ? B1l : B2l);

    // per-lane global src; LDS is linear in lane order (elem = 8*tid per chunk)
    const size_t aoff0 = (size_t)(m0 + wid * 16 + (lane >> 2)) * DMODEL + (lane & 3) * 8;
    const size_t boff0 = (size_t)(n0 + wid * 16 + (lane >> 2)) * DMODEL + (lane & 3) * 8;
    const int ldsw = wid * 512;   // wave-uniform LDS base (elems)

    f32x4 acc[4][4] = {};
    const int fr = lane & 15;
    const int fk = (lane >> 4) * 8;

    for (int t = 0; t < DMODEL / 32; ++t) {
        const size_t ko = (size_t)t * 32;
        __syncthreads();   // consumers done with LDS
        gload16(Ah_g + aoff0 + ko, &Ah[ldsw]);
        gload16(Ah_g + aoff0 + (size_t)64 * DMODEL + ko, &Ah[2048 + ldsw]);
        gload16(Al_g + aoff0 + ko, &Al[ldsw]);
        gload16(Al_g + aoff0 + (size_t)64 * DMODEL + ko, &Al[2048 + ldsw]);
        gload16(Bh_g + boff0 + ko, &Bh[ldsw]);
        gload16(Bh_g + boff0 + (size_t)64 * DMODEL + ko, &Bh[2048 + ldsw]);
        gload16(Bl_g + boff0 + ko, &Bl[ldsw]);
        gload16(Bl_g + boff0 + (size_t)64 * DMODEL + ko, &Bl[2048 + ldsw]);
        __syncthreads();   // vmcnt(0) drain + barrier -> data visible

        s16x8 fah[4], fal[4], fbh[4], fbl[4];
        #pragma unroll
        for (int mf = 0; mf < 4; ++mf) {
            int r = (wr * 64 + mf * 16 + fr) * 32 + fk;
            fah[mf] = *(const s16x8*)&Ah[r];
            fal[mf] = *(const s16x8*)&Al[r];
        }
        #pragma unroll
        for (int nf = 0; nf < 4; ++nf) {
            int r = (wc * 64 + nf * 16 + fr) * 32 + fk;
            fbh[nf] = *(const s16x8*)&Bh[r];
            fbl[nf] = *(const s16x8*)&Bl[r];
        }
        __builtin_amdgcn_s_setprio(1);
        #pragma unroll
        for (int mf = 0; mf < 4; ++mf)
            #pragma unroll
            for (int nf = 0; nf < 4; ++nf) {
                acc[mf][nf] = __builtin_amdgcn_mfma_f32_16x16x32_bf16(fah[mf], fbh[nf], acc[mf][nf], 0, 0, 0);
                acc[mf][nf] = __builtin_amdgcn_mfma_f32_16x16x32_bf16(fah[mf], fbl[nf], acc[mf][nf], 0, 0, 0);
                acc[mf][nf] = __builtin_amdgcn_mfma_f32_16x16x32_bf16(fal[mf], fbh[nf], acc[mf][nf], 0, 0, 0);
            }
        __builtin_amdgcn_s_setprio(0);
    }

    // epilogue: C/D layout col = lane&15, row = (lane>>4)*4 + r
    #pragma unroll
    for (int mf = 0; mf < 4; ++mf) {
        #pragma unroll
        for (int nf = 0; nf < 4; ++nf) {
            const int col = n0 + wc * 64 + nf * 16 + fr;
            if (mode == 1) {
                #pragma unroll
                for (int r = 0; r < 4; ++r) {
                    const int row = m0 + wr * 64 + mf * 16 + (lane >> 4) * 4 + r;
                    Yf[(size_t)row * DMODEL + col] = acc[mf][nf][r] + bias[col];
                }
            } else if (which == 2) {
                const int hh = col >> 6, d = col & 63;
                const int row0 = m0 + wr * 64 + mf * 16 + (lane >> 4) * 4;
                const int bb = row0 >> 11, ss = row0 & (SEQ - 1);
                const size_t idx = (((size_t)bb * NHEAD + hh) * HDIM + d) * SEQ + ss;
                ushort4 hv, lv;
                tsplit(acc[mf][nf][0], hv.x, lv.x);
                tsplit(acc[mf][nf][1], hv.y, lv.y);
                tsplit(acc[mf][nf][2], hv.z, lv.z);
                tsplit(acc[mf][nf][3], hv.w, lv.w);
                *(ushort4*)(Y2h + idx) = hv;
                *(ushort4*)(Y2l + idx) = lv;
            } else {
                unsigned short* Yh = which ? Y1h : Y0h;
                unsigned short* Yl = which ? Y1l : Y0l;
                const int hh = col >> 6, d = col & 63;
                #pragma unroll
                for (int r = 0; r < 4; ++r) {
                    const int row = m0 + wr * 64 + mf * 16 + (lane >> 4) * 4 + r;
                    const int bb = row >> 11, ss = row & (SEQ - 1);
                    const size_t idx = ((((size_t)bb * NHEAD + hh) * SEQ + ss) << 6) + d;
                    unsigned short hb, lb;
                    tsplit(acc[mf][nf][r], hb, lb);
                    Yh[idx] = hb;
                    Yl[idx] = lb;
                }
            }
        }
    }
}

// ---------------------------------------------------------------------------
// MFMA flash attention, swapped QK^T (scores transposed -> lane owns q-row).
// Grid (NT/2, B*H), 256 thr = 4 waves; block does Q-tile pair {pi, NT-1-pi}
// (uniform 33 j-tiles). K/V staged via reg prefetch; P in its OWN LDS buffer
// (2 barriers/tile, prefetch flies across whole tile). PAD=68: staging,
// frag-read and P b64-write patterns all bank-conflict-free.
// ---------------------------------------------------------------------------
__global__ __launch_bounds__(256, 2) void attn_mfma(
    const unsigned short* __restrict__ Qh_g, const unsigned short* __restrict__ Ql_g,
    const unsigned short* __restrict__ Kh_g, const unsigned short* __restrict__ Kl_g,
    const unsigned short* __restrict__ Vth_g, const unsigned short* __restrict__ Vtl_g,
    const float* __restrict__ pos_emb,
    unsigned short* __restrict__ Oh_g, unsigned short* __restrict__ Ol_g)
{
    __shared__ __align__(16) unsigned short klh[64 * PAD], kll[64 * PAD];  // K tile
    __shared__ __align__(16) unsigned short vth[64 * PAD], vtl[64 * PAD];  // V^T [d][j]
    __shared__ __align__(16) unsigned short plh[64 * PAD], pll[64 * PAD];  // P [q][j]
    __shared__ float pe[2 * MAXP + 1];

    const int tid = threadIdx.x;
    const int lane = tid & 63, w = tid >> 6;
    const int pi = blockIdx.x, bh = blockIdx.y;
    const int b = bh >> 4, h = bh & 15;

    const size_t hboff = ((size_t)b * NHEAD + h) * SEQ * HDIM;
    const unsigned short* Qh = Qh_g + hboff;
    const unsigned short* Ql = Ql_g + hboff;
    const unsigned short* Kh = Kh_g + hboff;
    const unsigned short* Kl = Kl_g + hboff;
    const unsigned short* Vth = Vth_g + hboff;   // [HDIM][SEQ]
    const unsigned short* Vtl = Vtl_g + hboff;

    for (int e = tid; e <= 2 * MAXP; e += 256)
        pe[e] = pos_emb[(size_t)e * NHEAD + h];
    __syncthreads();
    const float pe0 = pe[0];

    const int fr = lane & 15;          // frag row/col within 16
    const int g = lane >> 4;           // k-group / C-layout row group
    const int fko = g * 8;

    const int strow = tid >> 3;        // staging row 0..31 (+32)
    const int std0 = (tid & 7) * 8;    // staging 16B chunk (elems)

    uint4 rkh0, rkh1, rkl0, rkl1, rvh0, rvh1, rvl0, rvl1;
#define LDREGS(J0) do {                                                         \
    const unsigned short* kp_ = Kh + (size_t)((J0) + strow) * HDIM + std0;      \
    rkh0 = *(const uint4*)kp_;  rkh1 = *(const uint4*)(kp_ + 32 * HDIM);        \
    const unsigned short* klp_ = Kl + (size_t)((J0) + strow) * HDIM + std0;     \
    rkl0 = *(const uint4*)klp_; rkl1 = *(const uint4*)(klp_ + 32 * HDIM);       \
    const unsigned short* vhp_ = Vth + (size_t)strow * SEQ + (J0) + std0;       \
    rvh0 = *(const uint4*)vhp_; rvh1 = *(const uint4*)(vhp_ + 32 * SEQ);        \
    const unsigned short* vlp_ = Vtl + (size_t)strow * SEQ + (J0) + std0;       \
    rvl0 = *(const uint4*)vlp_; rvl1 = *(const uint4*)(vlp_ + 32 * SEQ);        \
} while (0)

    for (int half = 0; half < 2; ++half) {
        const int qt = half ? (NT - 1 - pi) : pi;
        const int i0 = qt * 64;
        const int ig = i0 + w * 16 + fr;   // this lane's q row

        // Q fragments: frag row = fr, k = fko + ks*32 (identical A/B mapping)
        s16x8 qfh[2], qfl[2];
        {
            const size_t qrow = (size_t)(i0 + w * 16 + fr) * HDIM;
            qfh[0] = *(const s16x8*)(Qh + qrow + fko);
            qfh[1] = *(const s16x8*)(Qh + qrow + 32 + fko);
            qfl[0] = *(const s16x8*)(Ql + qrow + fko);
            qfl[1] = *(const s16x8*)(Ql + qrow + 32 + fko);
        }

        f32x4 oacc[4] = {};
        float m_r = -INFINITY, l_r = 0.f;

        LDREGS(0);

        for (int tj = 0; tj <= qt; ++tj) {
            const int j0 = tj * 64;
            __syncthreads();   // (1) prior-iter K/V LDS readers done
            *(uint4*)&klh[strow * PAD + std0] = rkh0;
            *(uint4*)&klh[(strow + 32) * PAD + std0] = rkh1;
            *(uint4*)&kll[strow * PAD + std0] = rkl0;
            *(uint4*)&kll[(strow + 32) * PAD + std0] = rkl1;
            *(uint4*)&vth[strow * PAD + std0] = rvh0;
            *(uint4*)&vth[(strow + 32) * PAD + std0] = rvh1;
            *(uint4*)&vtl[strow * PAD + std0] = rvl0;
            *(uint4*)&vtl[(strow + 32) * PAD + std0] = rvl1;
            __syncthreads();   // (2) staging visible
            if (tj < qt) LDREGS(j0 + 64);   // prefetch flies until next (1)

            // ---- swapped QK^T: s[nf][r] = score[j=j0+nf*16+g*4+r][q=ig]
            f32x4 s[4] = {};
            __builtin_amdgcn_s_setprio(1);
            #pragma unroll
            for (int ks = 0; ks < 2; ++ks) {
                #pragma unroll
                for (int nf = 0; nf < 4; ++nf) {
                    const int ka = (nf * 16 + fr) * PAD + ks * 32 + fko;
                    s16x8 kbh = *(const s16x8*)&klh[ka];
                    s16x8 kbl = *(const s16x8*)&kll[ka];
                    s[nf] = __builtin_amdgcn_mfma_f32_16x16x32_bf16(kbh, qfh[ks], s[nf], 0, 0, 0);
                    s[nf] = __builtin_amdgcn_mfma_f32_16x16x32_bf16(kbl, qfh[ks], s[nf], 0, 0, 0);
                    s[nf] = __builtin_amdgcn_mfma_f32_16x16x32_bf16(kbh, qfl[ks], s[nf], 0, 0, 0);
                }
            }
            __builtin_amdgcn_s_setprio(0);

            // ---- bias + mask; row state is lane-local (q = fr across g-lanes)
            float pmax = -INFINITY;
            if (qt - tj >= 9) {
                const float c0 = 1e-9f + pe0;   // all rel <= -512
                #pragma unroll
                for (int nf = 0; nf < 4; ++nf)
                    #pragma unroll
                    for (int r = 0; r < 4; ++r) {
                        const float sv = s[nf][r] * 0.125f + c0;
                        s[nf][r] = sv;
                        pmax = fmaxf(pmax, sv);
                    }
            } else if (tj < qt) {
                #pragma unroll
                for (int nf = 0; nf < 4; ++nf) {
                    const int jb = j0 + nf * 16 + g * 4;
                    #pragma unroll
                    for (int r = 0; r < 4; ++r) {
                        int rel = jb + r - ig;
                        rel = rel < -MAXP ? -MAXP : rel;
                        const float sv = s[nf][r] * 0.125f + 1e-9f + pe[rel + MAXP];
                        s[nf][r] = sv;
                        pmax = fmaxf(pmax, sv);
                    }
                }
            } else {
                #pragma unroll
                for (int nf = 0; nf < 4; ++nf) {
                    const int jb = j0 + nf * 16 + g * 4;
                    #pragma unroll
                    for (int r = 0; r < 4; ++r) {
                        const int jg = jb + r;
                        float sv = s[nf][r] * 0.125f + 1e-9f + pe[jg - ig + MAXP];
                        sv = (jg > ig) ? -INFINITY : sv;
                        s[nf][r] = sv;
                        pmax = fmaxf(pmax, sv);
                    }
                }
            }
            // full-row reduce: only across the 4 g-lanes sharing this q-row
            pmax = fmaxf(pmax, __shfl_xor(pmax, 16, 64));
            pmax = fmaxf(pmax, __shfl_xor(pmax, 32, 64));
            const float mnew = fmaxf(m_r, pmax);
            const float fac = __expf(m_r - mnew);
            m_r = mnew;
            float lsum = 0.f;
            #pragma unroll
            for (int nf = 0; nf < 4; ++nf)
                #pragma unroll
                for (int r = 0; r < 4; ++r) {
                    const float p = __expf(s[nf][r] - mnew);
                    s[nf][r] = p;
                    lsum += p;
                }
            lsum += __shfl_xor(lsum, 16, 64);
            lsum += __shfl_xor(lsum, 32, 64);
            l_r = l_r * fac + lsum;
            // rescale O (O-frag rows are q = g*4+r -> broadcast fac from lane g*4+r)
            #pragma unroll
            for (int r = 0; r < 4; ++r) {
                const float facq = __shfl(fac, g * 4 + r, 64);
                #pragma unroll
                for (int nf = 0; nf < 4; ++nf) oacc[nf][r] *= facq;
            }
            // ---- pack P (wave-local rows, own buffer, b64 conflict-free)
            const int prow = (w * 16 + fr) * PAD;
            #pragma unroll
            for (int nf = 0; nf < 4; ++nf) {
                ushort4 h4, l4;
                tsplit(s[nf][0], h4.x, l4.x);
                tsplit(s[nf][1], h4.y, l4.y);
                tsplit(s[nf][2], h4.z, l4.z);
                tsplit(s[nf][3], h4.w, l4.w);
                *(ushort4*)&plh[prow + nf * 16 + g * 4] = h4;
                *(ushort4*)&pll[prow + nf * 16 + g * 4] = l4;
            }

            // ---- PV: oacc[nf] += P(q rows) * V^T(d = nf*16+fr)
            __builtin_amdgcn_s_setprio(1);
            #pragma unroll
            for (int ks = 0; ks < 2; ++ks) {
                const int pa = prow + ks * 32 + fko;
                s16x8 pah = *(const s16x8*)&plh[pa];
                s16x8 pal = *(const s16x8*)&pll[pa];
                #pragma unroll
                for (int nf = 0; nf < 4; ++nf) {
                    const int va = (nf * 16 + fr) * PAD + ks * 32 + fko;
                    s16x8 vbh = *(const s16x8*)&vth[va];
                    s16x8 vbl = *(const s16x8*)&vtl[va];
                    oacc[nf] = __builtin_amdgcn_mfma_f32_16x16x32_bf16(pah, vbh, oacc[nf], 0, 0, 0);
                    oacc[nf] = __builtin_amdgcn_mfma_f32_16x16x32_bf16(pah, vbl, oacc[nf], 0, 0, 0);
                    oacc[nf] = __builtin_amdgcn_mfma_f32_16x16x32_bf16(pal, vbh, oacc[nf], 0, 0, 0);
                }
            }
            __builtin_amdgcn_s_setprio(0);
        }

        // ---- normalize + write split O [M, DMODEL] (merge heads)
        const float linv = 1.0f / l_r;
        #pragma unroll
        for (int r = 0; r < 4; ++r) {
            const float invq = __shfl(linv, g * 4 + r, 64);
            const size_t m = (size_t)b * SEQ + i0 + w * 16 + g * 4 + r;
            #pragma unroll
            for (int nf = 0; nf < 4; ++nf) {
                const size_t idx = m * DMODEL + h * HDIM + nf * 16 + fr;
                unsigned short hv, lv;
                tsplit(oacc[nf][r] * invq, hv, lv);
                Oh_g[idx] = hv;
                Ol_g[idx] = lv;
            }
        }
    }
#undef LDREGS
}

// ---------------------------------------------------------------------------
extern "C" void kernel_launch(void* const* d_in, const int* in_sizes, int n_in,
                              void* d_out, int out_size, void* d_ws, size_t ws_size,
                              hipStream_t stream) {
    const float* x   = (const float*)d_in[0];
    const float* Wq  = (const float*)d_in[1];
    const float* Wk  = (const float*)d_in[2];
    const float* Wv  = (const float*)d_in[3];
    const float* Wo  = (const float*)d_in[4];
    const float* bo  = (const float*)d_in[5];
    const float* pem = (const float*)d_in[6];
    float* out = (float*)d_out;

    char* w = (char*)d_ws;
    const size_t MB = 1 << 20;
    unsigned short* oh  = (unsigned short*)(w + 0 * MB);    // 8 MB each
    unsigned short* ol  = (unsigned short*)(w + 8 * MB);
    unsigned short* qh  = (unsigned short*)(w + 16 * MB);
    unsigned short* ql  = (unsigned short*)(w + 24 * MB);
    unsigned short* kh  = (unsigned short*)(w + 32 * MB);
    unsigned short* kl  = (unsigned short*)(w + 40 * MB);
    unsigned short* vth = (unsigned short*)(w + 48 * MB);   // V^T [B,H,HD,S]
    unsigned short* vtl = (unsigned short*)(w + 56 * MB);
    unsigned short* Xh  = (unsigned short*)(w + 64 * MB);
    unsigned short* Xl  = (unsigned short*)(w + 72 * MB);
    unsigned short* Wqh = (unsigned short*)(w + 80 * MB);   // 2 MB each (transposed)
    unsigned short* Wql = (unsigned short*)(w + 82 * MB);
    unsigned short* Wkh = (unsigned short*)(w + 84 * MB);
    unsigned short* Wkl = (unsigned short*)(w + 86 * MB);
    unsigned short* Wvh = (unsigned short*)(w + 88 * MB);
    unsigned short* Wvl = (unsigned short*)(w + 90 * MB);
    unsigned short* Woh = (unsigned short*)(w + 92 * MB);
    unsigned short* Wol = (unsigned short*)(w + 94 * MB);

    const int nX4 = MTOT * DMODEL / 4;
    split_rows<<<dim3(nX4 / 256), 256, 0, stream>>>(x, Xh, Xl, nX4);

    dim3 tg(32, 32);
    split_transpose<<<tg, 256, 0, stream>>>(Wq, Wqh, Wql);
    split_transpose<<<tg, 256, 0, stream>>>(Wk, Wkh, Wkl);
    split_transpose<<<tg, 256, 0, stream>>>(Wv, Wvh, Wvl);
    split_transpose<<<tg, 256, 0, stream>>>(Wo, Woh, Wol);

    // fused QKV projection: 24 n-tiles (3 weights x 8) x 32 m-tiles = 768 blocks
    dim3 gq(24, MTOT / 128);
    gemm_mfma<<<gq, 256, 0, stream>>>(Xh, Xl,
                                      Wqh, Wql, Wkh, Wkl, Wvh, Wvl,
                                      nullptr, nullptr,
                                      qh, ql, kh, kl, vth, vtl, 0);

    attn_mfma<<<dim3(NT / 2, NBATCH * NHEAD), 256, 0, stream>>>(
        qh, ql, kh, kl, vth, vtl, pem, oh, ol);

    dim3 go(DMODEL / 128, MTOT / 128);
    gemm_mfma<<<go, 256, 0, stream>>>(oh, ol,
                                      Woh, Wol, nullptr, nullptr, nullptr, nullptr,
                                      bo, out,
                                      nullptr, nullptr, nullptr, nullptr, nullptr, nullptr, 1);
}